// Round 1
// 484.912 us; speedup vs baseline: 1.0549x; 1.0549x over previous
//
#include <hip/hip_runtime.h>
#include <math.h>

#define BLOCK 512
#define TILE_R 64
#define LIN 592
// Shared buffer serves two roles per block (separated by barriers):
//   xs: input tile,  [TILE_R][SEGC+1]        (odd stride -> conflict-free lane=row reads)
//   ys: output tile, [SEGC][TILE_R+1] (col-major, stride 65 -> conflict-free staging)
// max over segments: seg1 ys = 192*65 = 12480 floats = 49.92 KB -> 3 blocks/CU
#define LDS_FLOATS 12480

// smooth_leaky_relu(x) = x*(0.2 + 0.8*sigmoid(x))
__device__ __forceinline__ float slr(float v) {
    float s = 1.0f / (1.0f + __expf(-v));
    return v * (0.2f + 0.8f * s);
}

// One block handles one (row-tile, segment) pair: stage 64 rows of the segment
// into LDS, one barrier, 8 waves compute MUL/8 contiguous outputs per lane-row,
// then stage outputs back through LDS (column-major) so the global store is
// fully coalesced (consecutive lanes -> consecutive addresses).
template<int MUL, int D, int C0, int MB, bool ACT>
__device__ __forceinline__ void seg_compute(
    float* __restrict__ xs,
    const float* __restrict__ x,
    const float* __restrict__ w,   // [MUL, MUL] row-major (o, m)
    const float* __restrict__ b,   // [MUL]
    float* __restrict__ out,
    int n0, int N, int tid, int lane, int wv)
{
    constexpr int SEGC = MUL * D;       // columns in this segment
    constexpr int S    = SEGC + 1;      // xs row stride (odd -> bank-spread)
    constexpr int OPW  = MUL / 8;       // outputs (o) per wave (8 waves)
    constexpr int TR1  = TILE_R + 1;    // ys column stride (odd -> bank-spread)

    // ---- stage in: global -> LDS, coalesced float4 ----
    constexpr int CH = SEGC / 4;        // float4 chunks per row
    constexpr int F4 = TILE_R * CH;
    #pragma unroll 1
    for (int i = tid; i < F4; i += BLOCK) {
        int r  = i / CH;                // constexpr divisor -> magic mul
        int cb = i - r * CH;
        int gr = n0 + r;
        float4 v = make_float4(0.f, 0.f, 0.f, 0.f);
        if (gr < N) v = *(const float4*)(x + (size_t)gr * LIN + C0 + cb * 4);
        float* dst = xs + r * S + cb * 4;
        dst[0] = v.x; dst[1] = v.y; dst[2] = v.z; dst[3] = v.w;
    }
    __syncthreads();

    // ---- compute: acc[oo][j] = b[o] + sum_m w[o][m] * xs[lane][m*D+j] ----
    float acc[OPW * D];
    #pragma unroll
    for (int oo = 0; oo < OPW; ++oo) {
        float bv = b[wv * OPW + oo];            // wave-uniform -> s_load
        #pragma unroll
        for (int j = 0; j < D; ++j) acc[oo * D + j] = bv;
    }

    const float* xrow = xs + lane * S;
    #pragma unroll 1
    for (int mb = 0; mb < MUL; mb += MB) {
        float xv[MB * D];
        #pragma unroll
        for (int k = 0; k < MB * D; ++k) xv[k] = xrow[mb * D + k];
        #pragma unroll
        for (int oo = 0; oo < OPW; ++oo) {
            const float* wr = w + (wv * OPW + oo) * MUL + mb;  // uniform -> s_load
            #pragma unroll
            for (int mm = 0; mm < MB; ++mm) {
                float wval = wr[mm];
                #pragma unroll
                for (int j = 0; j < D; ++j)
                    acc[oo * D + j] = fmaf(wval, xv[mm * D + j], acc[oo * D + j]);
            }
        }
    }

    if (ACT) {
        #pragma unroll
        for (int i = 0; i < OPW * D; ++i) acc[i] = slr(acc[i]);
    }

    // ---- stage out: acc -> ys (column-major in the same LDS buffer) ----
    __syncthreads();                    // all xs reads complete before overwrite
    {
        int c0w = wv * (OPW * D);       // wave's first column in the segment
        #pragma unroll
        for (int i = 0; i < OPW * D; ++i)
            xs[(c0w + i) * TR1 + lane] = acc[i];   // banks (c+lane)%32: conflict-free
    }
    __syncthreads();

    // ---- store: consecutive lanes -> consecutive c -> coalesced 256B/inst ----
    constexpr int TOT = TILE_R * SEGC;
    #pragma unroll 1
    for (int i = tid; i < TOT; i += BLOCK) {
        int r = i / SEGC;               // constexpr divisor -> magic mul
        int c = i - r * SEGC;
        int row = n0 + r;
        if (row < N)
            out[(size_t)row * LIN + C0 + c] = xs[c * TR1 + r];  // banks (c+r)%32: conflict-free
    }
}

__global__ __launch_bounds__(BLOCK, 6)
void irreps_kernel(const float* __restrict__ x,
                   const float* __restrict__ w0, const float* __restrict__ w1,
                   const float* __restrict__ w2, const float* __restrict__ w3,
                   const float* __restrict__ b0, const float* __restrict__ b1,
                   const float* __restrict__ b2, const float* __restrict__ b3,
                   float* __restrict__ out, int N)
{
    __shared__ float xs[LDS_FLOATS];    // 49.92 KB -> 3 blocks/CU, 24 waves/CU
    int tid  = threadIdx.x;
    int lane = tid & 63;
    int wv   = __builtin_amdgcn_readfirstlane(tid >> 6);  // wave id, uniform
    int n0   = blockIdx.x * TILE_R;

    switch (blockIdx.y) {
    case 0: seg_compute<128, 1,   0, 16, true >(xs, x, w0, b0, out, n0, N, tid, lane, wv); break;
    case 1: seg_compute< 64, 3, 128,  8, false>(xs, x, w1, b1, out, n0, N, tid, lane, wv); break;
    case 2: seg_compute< 32, 5, 320,  4, false>(xs, x, w2, b2, out, n0, N, tid, lane, wv); break;
    default:seg_compute< 16, 7, 480,  4, false>(xs, x, w3, b3, out, n0, N, tid, lane, wv); break;
    }
}

extern "C" void kernel_launch(void* const* d_in, const int* in_sizes, int n_in,
                              void* d_out, int out_size, void* d_ws, size_t ws_size,
                              hipStream_t stream) {
    const float* x  = (const float*)d_in[0];
    const float* w0 = (const float*)d_in[1];
    const float* w1 = (const float*)d_in[2];
    const float* w2 = (const float*)d_in[3];
    const float* w3 = (const float*)d_in[4];
    const float* b0 = (const float*)d_in[5];
    const float* b1 = (const float*)d_in[6];
    const float* b2 = (const float*)d_in[7];
    const float* b3 = (const float*)d_in[8];
    float* out = (float*)d_out;

    int N = in_sizes[0] / LIN;                      // 100000
    dim3 grid((N + TILE_R - 1) / TILE_R, 4);        // 1563 x 4 independent blocks
    irreps_kernel<<<grid, BLOCK, 0, stream>>>(x, w0, w1, w2, w3,
                                              b0, b1, b2, b3, out, N);
}

// Round 3
// 484.284 us; speedup vs baseline: 1.0563x; 1.0013x over previous
//
#include <hip/hip_runtime.h>
#include <math.h>

#define BLOCK 512
#define TILE_R 64
#define LIN 592
// LDS: one tile, float4-swizzled: chunk (r,c4) at float4-index r*CHP + (c4 ^ (r&7)),
// CHP = CH rounded up to a multiple of 8 so the XOR is closed within a row
// (seg3 has CH=28 -> CHP=32; others already multiples of 8).
// 16B-aligned everywhere -> ds_read/write_b128; XOR spreads banks (conflict-free
// for lane=row column access AND linear row-major sweeps). Max: seg1 64*48 f4 = 48KB.
#define LDS_FLOATS (64 * 48 * 4)

// smooth_leaky_relu(x) = x*(0.2 + 0.8*sigmoid(x))
__device__ __forceinline__ float slr(float v) {
    float s = 1.0f / (1.0f + __expf(-v));
    return v * (0.2f + 0.8f * s);
}

template<int MUL, int D, int C0, int MB, bool ACT>
__device__ __forceinline__ void seg_compute(
    float* __restrict__ xs,
    const float* __restrict__ x,
    const float* __restrict__ w,   // [MUL, MUL] row-major (o, m)
    const float* __restrict__ b,   // [MUL]
    float* __restrict__ out,
    int n0, int N, int tid, int lane, int wv)
{
    constexpr int SEGC = MUL * D;            // columns in this segment
    constexpr int CH   = SEGC / 4;           // real float4 chunks per row (32/48/40/28)
    constexpr int CHP  = (CH + 7) & ~7;      // padded LDS row stride (32/48/40/32)
    constexpr int OPW  = MUL / 8;            // outputs (o) per wave (8 waves)
    float4* xs4 = (float4*)xs;

    // ---- stage in: global -> LDS, b128 both sides ----
    constexpr int F4 = TILE_R * CH;
    #pragma unroll 1
    for (int i = tid; i < F4; i += BLOCK) {
        int r  = i / CH;                     // constexpr divisor -> magic mul
        int c4 = i - r * CH;
        int gr = n0 + r;
        float4 v = make_float4(0.f, 0.f, 0.f, 0.f);
        if (gr < N) v = *(const float4*)(x + (size_t)gr * LIN + C0 + c4 * 4);
        xs4[r * CHP + (c4 ^ (r & 7))] = v;
    }
    __syncthreads();

    // ---- compute: acc[oo][j] = b[o] + sum_m w[o][m] * x[lane][m*D+j] ----
    float acc[OPW * D];
    #pragma unroll
    for (int oo = 0; oo < OPW; ++oo) {
        float bv = b[wv * OPW + oo];            // wave-uniform -> s_load
        #pragma unroll
        for (int j = 0; j < D; ++j) acc[oo * D + j] = bv;
    }

    const int rbase = lane * CHP;
    const int sw    = lane & 7;
    #pragma unroll 1
    for (int mb = 0; mb < MUL; mb += MB) {
        float xv[MB * D];
        #pragma unroll
        for (int k4 = 0; k4 < (MB * D) / 4; ++k4) {   // b128 reads, conflict-free
            float4 v = xs4[rbase + (((mb * D) / 4 + k4) ^ sw)];
            xv[4*k4+0] = v.x; xv[4*k4+1] = v.y; xv[4*k4+2] = v.z; xv[4*k4+3] = v.w;
        }
        #pragma unroll
        for (int oo = 0; oo < OPW; ++oo) {
            const float* wr = w + (wv * OPW + oo) * MUL + mb;  // uniform -> s_load
            #pragma unroll
            for (int mm = 0; mm < MB; ++mm) {
                float wval = wr[mm];
                #pragma unroll
                for (int j = 0; j < D; ++j)
                    acc[oo * D + j] = fmaf(wval, xv[mm * D + j], acc[oo * D + j]);
            }
        }
    }

    if (ACT) {
        #pragma unroll
        for (int i = 0; i < OPW * D; ++i) acc[i] = slr(acc[i]);
    }

    // ---- stage out: acc -> same LDS tile (same swizzled layout) ----
    __syncthreads();                    // all xs reads complete before overwrite
    if constexpr ((OPW * D) % 4 == 0) {
        constexpr int K4 = (OPW * D) / 4;
        int c0 = wv * K4;               // wave's first chunk column
        #pragma unroll
        for (int k4 = 0; k4 < K4; ++k4) {
            float4 v = make_float4(acc[4*k4], acc[4*k4+1], acc[4*k4+2], acc[4*k4+3]);
            xs4[rbase + ((c0 + k4) ^ sw)] = v;  // b128, conflict-free
        }
    } else {                            // seg3: OPW*D=14, scalar fallback (small)
        int c0 = wv * (OPW * D);
        #pragma unroll
        for (int i = 0; i < OPW * D; ++i) {
            int c = c0 + i;
            xs[(rbase + ((c >> 2) ^ sw)) * 4 + (c & 3)] = acc[i];
        }
    }
    __syncthreads();

    // ---- store: b128 LDS reads + fully coalesced b128 global stores ----
    #pragma unroll 1
    for (int i = tid; i < F4; i += BLOCK) {
        int r  = i / CH;
        int c4 = i - r * CH;
        int row = n0 + r;
        float4 v = xs4[r * CHP + (c4 ^ (r & 7))];
        if (row < N)
            *(float4*)(out + (size_t)row * LIN + C0 + c4 * 4) = v;
    }
}

__global__ __launch_bounds__(BLOCK, 6)
void irreps_kernel(const float* __restrict__ x,
                   const float* __restrict__ w0, const float* __restrict__ w1,
                   const float* __restrict__ w2, const float* __restrict__ w3,
                   const float* __restrict__ b0, const float* __restrict__ b1,
                   const float* __restrict__ b2, const float* __restrict__ b3,
                   float* __restrict__ out, int N)
{
    __shared__ float xs[LDS_FLOATS];    // 48 KB -> 3 blocks/CU, 24 waves/CU
    int tid  = threadIdx.x;
    int lane = tid & 63;
    int wv   = __builtin_amdgcn_readfirstlane(tid >> 6);  // wave id, uniform
    int n0   = blockIdx.x * TILE_R;

    switch (blockIdx.y) {
    case 0: seg_compute<128, 1,   0, 16, true >(xs, x, w0, b0, out, n0, N, tid, lane, wv); break;
    case 1: seg_compute< 64, 3, 128,  8, false>(xs, x, w1, b1, out, n0, N, tid, lane, wv); break;
    case 2: seg_compute< 32, 5, 320,  4, false>(xs, x, w2, b2, out, n0, N, tid, lane, wv); break;
    default:seg_compute< 16, 7, 480,  4, false>(xs, x, w3, b3, out, n0, N, tid, lane, wv); break;
    }
}

extern "C" void kernel_launch(void* const* d_in, const int* in_sizes, int n_in,
                              void* d_out, int out_size, void* d_ws, size_t ws_size,
                              hipStream_t stream) {
    const float* x  = (const float*)d_in[0];
    const float* w0 = (const float*)d_in[1];
    const float* w1 = (const float*)d_in[2];
    const float* w2 = (const float*)d_in[3];
    const float* w3 = (const float*)d_in[4];
    const float* b0 = (const float*)d_in[5];
    const float* b1 = (const float*)d_in[6];
    const float* b2 = (const float*)d_in[7];
    const float* b3 = (const float*)d_in[8];
    float* out = (float*)d_out;

    int N = in_sizes[0] / LIN;                      // 100000
    dim3 grid((N + TILE_R - 1) / TILE_R, 4);        // 1563 x 4 independent blocks
    irreps_kernel<<<grid, BLOCK, 0, stream>>>(x, w0, w1, w2, w3,
                                              b0, b1, b2, b3, out, N);
}